// Round 8
// baseline (239.809 us; speedup 1.0000x reference)
//
#include <hip/hip_runtime.h>

#define NB 32
#define NPRED 65536
#define NGT 64
#define BLK 256
#define SLICES 64              // == NGT == lanes, finisher reduction relies on this
#define PPT 4                  // preds per thread; block covers 1024 preds
#define NCB 128                // cumulative bins of 5px
#define CBIN_SCALE 0.2f        // 1/5

#define POS_THR 0.5f
#define NEG_THR 0.4f
#define SCAT_THR 0.1f
#define EPSF 1e-6f

// ---------- exact-op helpers ----------
// Comparison-feeding arithmetic (iou) must be bit-exact vs NumPy fp32 (no FMA
// contraction, IEEE div). Sum-only terms (focal/giou weights) tolerate ulp drift.

__device__ __forceinline__ int cbin(float x) {
    int bi = (int)(x * CBIN_SCALE);         // trunc; monotone non-decreasing
    return max(0, min(NCB - 1, bi));        // clamp keeps monotone -> superset safe
}

__device__ __forceinline__ float focal_shared(float l, bool pos) {
    float e  = expf(-fabsf(l));
    float lg = log1pf(e);
    float rp = 1.f / (1.f + e);              // sigmoid(|l|)
    float p  = (l >= 0.f) ? rp : (1.f - rp); // sigmoid(l); sum-only term
    if (pos) { float q = 1.f - p; return 0.25f * q * q * ((fmaxf(l, 0.f) - l) + lg); }
    return 0.75f * p * p * (fmaxf(l, 0.f) + lg);
}

__device__ __forceinline__ float giou_term(float px1, float py1, float px2, float py2,
                                           float gx1, float gy1, float gx2, float gy2) {
    float x1 = fmaxf(px1, gx1), y1 = fmaxf(py1, gy1);
    float x2 = fminf(px2, gx2), y2 = fminf(py2, gy2);
    float dx = fmaxf(__fsub_rn(x2, x1), 0.f);
    float dy = fmaxf(__fsub_rn(y2, y1), 0.f);
    float inter = __fmul_rn(dx, dy);
    float ap = __fmul_rn(__fsub_rn(px2, px1), __fsub_rn(py2, py1));
    float ag = __fmul_rn(__fsub_rn(gx2, gx1), __fsub_rn(gy2, gy1));
    float uni = __fsub_rn(__fadd_rn(ap, ag), inter);
    float iou = __fdiv_rn(inter, fmaxf(uni, EPSF));
    float ex1 = fminf(px1, gx1), ey1 = fminf(py1, gy1);
    float ex2 = fmaxf(px2, gx2), ey2 = fmaxf(py2, gy2);
    float enc = __fmul_rn(__fsub_rn(ex2, ex1), __fsub_rn(ey2, ey1));
    float giou = __fsub_rn(iou, __fdiv_rn(__fsub_rn(enc, uni), fmaxf(enc, EPSF)));
    return __fsub_rn(1.f, giou);
}

// ---------- fused kernel: main pass + per-image finisher + final scalar ----------

__global__ __launch_bounds__(BLK) void fused(
    const float* __restrict__ pred, const float* __restrict__ gt,
    unsigned long long* keys2,                   // [NB][SLICES][NGT] plain-stored
    float* Sfl2, float* Sgt2, int* Svp2,         // [NB][SLICES] plain-stored
    float* cls_b, float* reg_b, int* npos_b,
    unsigned* done_img, unsigned* done_final, float* out)
{
    const int b = blockIdx.y;
    const int slice = blockIdx.x;
    const int tid = threadIdx.x;
    const int lane = tid & 63;
    const int wv = tid >> 6;

    // SoA gt (65th entry = zero dummy for branchless inline slots)
    __shared__ float sgx1[NGT + 1], sgy1[NGT + 1], sgx2[NGT + 1], sgy2[NGT + 1], sgar[NGT + 1];
    __shared__ unsigned long long skey[NGT];       // 512 B
    // cumulative candidate masks: [0]=le_x1 (prefix), [1]=ge_x2 (suffix),
    //                             [2]=le_y1 (prefix), [3]=ge_y2 (suffix)
    __shared__ unsigned long long cums[4][NCB];    // 4 KiB
    __shared__ float rfl[BLK / 64], rgt[BLK / 64];
    __shared__ int rvp[BLK / 64];
    __shared__ unsigned cn_list[NGT];

    // ---- pred loads first: 5 aligned float4 per thread, in flight during setup ----
    const unsigned base_n = (unsigned)(slice * (BLK * PPT));
    const float4* src4 = (const float4*)(pred + (size_t)b * NPRED * 5 + (size_t)base_n * 5)
                         + (size_t)tid * 5;
    float4 q0 = src4[0], q1 = src4[1], q2 = src4[2], q3 = src4[3], q4 = src4[4];

    // ---- gt setup ----
    const float4* gtb = (const float4*)(gt + (size_t)b * NGT * 4);
    float4 gmine;
    if (tid < NGT) gmine = gtb[tid];
    // zero the 4 point arrays (512 ullong, 2 per thread)
    ((unsigned long long*)cums)[tid] = 0ULL;
    ((unsigned long long*)cums)[tid + BLK] = 0ULL;
    if (tid < NGT) {
        sgx1[tid] = gmine.x; sgy1[tid] = gmine.y;
        sgx2[tid] = gmine.z; sgy2[tid] = gmine.w;
        sgar[tid] = __fmul_rn(__fsub_rn(gmine.z, gmine.x), __fsub_rn(gmine.w, gmine.y));
        skey[tid] = 0ULL;
    } else if (tid == NGT) {
        sgx1[NGT] = 0.f; sgy1[NGT] = 0.f; sgx2[NGT] = 0.f; sgy2[NGT] = 0.f; sgar[NGT] = 0.f;
    }
    __syncthreads();

    // point inserts (wave 0 only)
    if (tid < NGT) {
        unsigned long long bit = 1ULL << tid;
        atomicOr(&cums[0][cbin(gmine.x)], bit);   // gx1 -> prefix array
        atomicOr(&cums[1][cbin(gmine.z)], bit);   // gx2 -> suffix array
        atomicOr(&cums[2][cbin(gmine.y)], bit);   // gy1 -> prefix array
        atomicOr(&cums[3][cbin(gmine.w)], bit);   // gy2 -> suffix array
    }
    __syncthreads();

    // wave-parallel cumulative OR: wave wv scans array wv (128 bins, 2/lane).
    {
        unsigned long long v0 = cums[wv][2 * lane];
        unsigned long long v1 = cums[wv][2 * lane + 1];
        unsigned long long v = v0 | v1;
        if ((wv & 1) == 0) {
            // prefix (le): inclusive scan low->high
            #pragma unroll
            for (int off = 1; off < 64; off <<= 1) {
                unsigned long long t = __shfl_up(v, off);
                if (lane >= off) v |= t;
            }
            unsigned long long prev = __shfl_up(v, 1);
            if (lane == 0) prev = 0ULL;
            cums[wv][2 * lane]     = prev | v0;
            cums[wv][2 * lane + 1] = v;
        } else {
            // suffix (ge): inclusive scan high->low
            #pragma unroll
            for (int off = 1; off < 64; off <<= 1) {
                unsigned long long t = __shfl_down(v, off);
                if (lane + off < 64) v |= t;
            }
            unsigned long long nxt = __shfl_down(v, 1);
            if (lane == 63) nxt = 0ULL;
            cums[wv][2 * lane]     = v;
            cums[wv][2 * lane + 1] = v1 | nxt;
        }
    }
    __syncthreads();

    // ---- unpack rows: thread t owns preds 4t..4t+3 (stride-5 in the 20 floats) ----
    const float cxa[PPT] = {q0.x, q1.y, q2.z, q3.w};
    const float cya[PPT] = {q0.y, q1.z, q2.w, q4.x};
    const float wa [PPT] = {q0.z, q1.w, q3.x, q4.y};
    const float ha [PPT] = {q0.w, q2.x, q3.y, q4.z};
    const float oba[PPT] = {q1.x, q2.y, q3.z, q4.w};

    float acc_fl = 0.f, acc_gt = 0.f;
    int acc_vp = 0;   // valid count | pos count<<16

    #pragma unroll
    for (int i = 0; i < PPT; ++i) {
        const float px1 = __fsub_rn(cxa[i], __fmul_rn(wa[i], 0.5f));
        const float py1 = __fsub_rn(cya[i], __fmul_rn(ha[i], 0.5f));
        const float px2 = __fadd_rn(cxa[i], __fmul_rn(wa[i], 0.5f));
        const float py2 = __fadd_rn(cya[i], __fmul_rn(ha[i], 0.5f));
        const float area_p = __fmul_rn(__fsub_rn(px2, px1), __fsub_rn(py2, py1));

        // 4-probe candidate mask (superset of true overlaps; exact gate below)
        unsigned long long m = (cums[1][cbin(px1)] & cums[0][cbin(px2)])
                             & (cums[3][cbin(py1)] & cums[2][cbin(py2)]);

        const unsigned n = base_n + (unsigned)(PPT * tid + i);
        const unsigned long long nkey = (unsigned long long)(~n);

        float best_iou = 0.f;   // zero row -> argmax 0, matches np.argmax
        int best_j = 0;

        // branchless inline-2: dummy index 64 (zero box) -> inter=0 -> no-op
        int j0 = NGT, j1 = NGT;
        if (m) { j0 = __ffsll(m) - 1; m &= m - 1; }
        if (m) { j1 = __ffsll(m) - 1; m &= m - 1; }
        {
            float ax1 = sgx1[j0], ay1 = sgy1[j0], ax2 = sgx2[j0], ay2 = sgy2[j0], aga = sgar[j0];
            float bx1 = sgx1[j1], by1 = sgy1[j1], bx2 = sgx2[j1], by2 = sgy2[j1], agb = sgar[j1];
            float x1 = fmaxf(px1, ax1), y1 = fmaxf(py1, ay1);
            float x2 = fminf(px2, ax2), y2 = fminf(py2, ay2);
            float dx = fmaxf(__fsub_rn(x2, x1), 0.f);
            float dy = fmaxf(__fsub_rn(y2, y1), 0.f);
            float inter = __fmul_rn(dx, dy);
            float uni = __fsub_rn(__fadd_rn(area_p, aga), inter);
            float iou = __fdiv_rn(inter, fmaxf(uni, EPSF));
            iou = (inter > 0.f) ? iou : 0.f;
            if (iou > best_iou) { best_iou = iou; best_j = j0; }
            if (iou > SCAT_THR)
                atomicMax(&skey[j0], (((unsigned long long)__float_as_uint(iou)) << 32) | nkey);

            float X1 = fmaxf(px1, bx1), Y1 = fmaxf(py1, by1);
            float X2 = fminf(px2, bx2), Y2 = fminf(py2, by2);
            float dX = fmaxf(__fsub_rn(X2, X1), 0.f);
            float dY = fmaxf(__fsub_rn(Y2, Y1), 0.f);
            float interB = __fmul_rn(dX, dY);
            float uniB = __fsub_rn(__fadd_rn(area_p, agb), interB);
            float iouB = __fdiv_rn(interB, fmaxf(uniB, EPSF));
            iouB = (interB > 0.f) ? iouB : 0.f;
            if (iouB > best_iou) { best_iou = iouB; best_j = j1; }
            if (iouB > SCAT_THR)
                atomicMax(&skey[j1], (((unsigned long long)__float_as_uint(iouB)) << 32) | nkey);
        }

        // rare remainder (2-way unrolled)
        while (m) {
            int ja = __ffsll(m) - 1; m &= m - 1;
            int jb = -1;
            if (m) { jb = __ffsll(m) - 1; m &= m - 1; }
            int jbc = (jb >= 0) ? jb : NGT;
            float ax1 = sgx1[ja], ay1 = sgy1[ja], ax2 = sgx2[ja], ay2 = sgy2[ja], aga = sgar[ja];
            float bx1 = sgx1[jbc], by1 = sgy1[jbc], bx2 = sgx2[jbc], by2 = sgy2[jbc], agb = sgar[jbc];
            {
                float x1 = fmaxf(px1, ax1), y1 = fmaxf(py1, ay1);
                float x2 = fminf(px2, ax2), y2 = fminf(py2, ay2);
                float dx = fmaxf(__fsub_rn(x2, x1), 0.f);
                float dy = fmaxf(__fsub_rn(y2, y1), 0.f);
                float inter = __fmul_rn(dx, dy);
                if (inter > 0.f) {
                    float uni = __fsub_rn(__fadd_rn(area_p, aga), inter);
                    float iou = __fdiv_rn(inter, fmaxf(uni, EPSF));
                    if (iou > best_iou) { best_iou = iou; best_j = ja; }
                    if (iou > SCAT_THR)
                        atomicMax(&skey[ja], (((unsigned long long)__float_as_uint(iou)) << 32) | nkey);
                }
            }
            if (jb >= 0) {
                float x1 = fmaxf(px1, bx1), y1 = fmaxf(py1, by1);
                float x2 = fminf(px2, bx2), y2 = fminf(py2, by2);
                float dx = fmaxf(__fsub_rn(x2, x1), 0.f);
                float dy = fmaxf(__fsub_rn(y2, y1), 0.f);
                float inter = __fmul_rn(dx, dy);
                if (inter > 0.f) {
                    float uni = __fsub_rn(__fadd_rn(area_p, agb), inter);
                    float iou = __fdiv_rn(inter, fmaxf(uni, EPSF));
                    if (iou > best_iou) { best_iou = iou; best_j = jb; }
                    if (iou > SCAT_THR)
                        atomicMax(&skey[jb], (((unsigned long long)__float_as_uint(iou)) << 32) | nkey);
                }
            }
        }

        const bool pos0   = best_iou > POS_THR;
        const bool negf   = best_iou < NEG_THR;
        const bool valid0 = pos0 || negf;
        if (valid0) acc_fl += focal_shared(oba[i], pos0);
        if (pos0) {
            acc_gt += giou_term(px1, py1, px2, py2,
                                sgx1[best_j], sgy1[best_j], sgx2[best_j], sgy2[best_j]);
        }
        acc_vp += (valid0 ? 1 : 0) | (pos0 ? 0x10000 : 0);
    }

    // block reduction
    for (int off = 32; off; off >>= 1) {
        acc_fl += __shfl_down(acc_fl, off);
        acc_gt += __shfl_down(acc_gt, off);
        acc_vp += __shfl_down(acc_vp, off);
    }
    if (lane == 0) { rfl[wv] = acc_fl; rgt[wv] = acc_gt; rvp[wv] = acc_vp; }
    __syncthreads();   // also orders all skey LDS atomics before the drain

    // ---- per-slice publication: plain stores, no init, no global atomics ----
    const int bs = b * SLICES + slice;
    if (tid == 0) {
        float sfl = 0.f, sgt2v = 0.f; int svp = 0;
        #pragma unroll
        for (int i = 0; i < BLK / 64; ++i) { sfl += rfl[i]; sgt2v += rgt[i]; svp += rvp[i]; }
        Sfl2[bs] = sfl; Sgt2[bs] = sgt2v; Svp2[bs] = svp;
    }
    if (tid < NGT) keys2[(size_t)bs * NGT + tid] = skey[tid];

    // release: fence all stores, then one thread bumps the per-image counter
    __threadfence();
    __syncthreads();
    unsigned cnt = 0;
    if (tid == 0) cnt = atomicAdd(&done_img[b], 1u);
    if (wv != 0) return;
    cnt = __shfl(cnt, 0);
    if (cnt != SLICES - 1) return;

    // ================= finisher (one wave, last-done block of image b) =================
    __threadfence();   // acquire

    // max key per gt over all slices (lane == gt index; coalesced 512 B rows)
    const unsigned long long* kb = keys2 + (size_t)b * SLICES * NGT;
    unsigned long long key = 0ULL;
    #pragma unroll 8
    for (int s = 0; s < SLICES; ++s) {
        unsigned long long k = kb[(size_t)s * NGT + lane];
        key = (k > key) ? k : key;   // same total order as global atomicMax before
    }
    float miou = __uint_as_float((unsigned)(key >> 32));
    unsigned n = ~((unsigned)(key & 0xFFFFFFFFULL));
    bool qual = (miou > SCAT_THR) && (n < NPRED);   // n-range check = OOB hardening;
                                                    // valid keys always have n < NPRED

    // dedupe: keep first qualifying lane per pred index (ref .at[].max semantics)
    bool unique = qual;
    for (int j2 = 0; j2 < NGT; ++j2) {
        unsigned bn = __shfl(n, j2);
        int bq = __shfl((int)qual, j2);
        if (bq && j2 < lane && bn == n) unique = false;
    }
    unsigned long long mask = __ballot(unique ? 1 : 0);
    int NC = __popcll(mask);
    int slot = __popcll(mask & ((1ULL << lane) - 1ULL));
    if (unique) cn_list[slot] = n;   // wave-synchronous LDS write->read (single wave)

    // candidate-parallel: lane l recomputes candidate l's full best_gt argmax
    float cx = 0.f, cy = 0.f, w = 0.f, h = 0.f, obj = 0.f;
    if (lane < NC) {
        const float* p = pred + (size_t)b * NPRED * 5 + (size_t)cn_list[lane] * 5;
        cx = p[0]; cy = p[1]; w = p[2]; h = p[3]; obj = p[4];
    }
    float px1 = __fsub_rn(cx, __fmul_rn(w, 0.5f));
    float py1 = __fsub_rn(cy, __fmul_rn(h, 0.5f));
    float px2 = __fadd_rn(cx, __fmul_rn(w, 0.5f));
    float py2 = __fadd_rn(cy, __fmul_rn(h, 0.5f));
    float area_p = __fmul_rn(__fsub_rn(px2, px1), __fsub_rn(py2, py1));

    float bv = 0.f; int bj = 0;
    #pragma unroll 4
    for (int j = 0; j < NGT; ++j) {
        // uniform scalar loads from this block's own gt SoA (still valid in LDS)
        float gx1 = sgx1[j], gy1 = sgy1[j], gx2 = sgx2[j], gy2 = sgy2[j];
        float x1 = fmaxf(px1, gx1), y1 = fmaxf(py1, gy1);
        float x2 = fminf(px2, gx2), y2 = fminf(py2, gy2);
        float dx = fmaxf(__fsub_rn(x2, x1), 0.f);
        float dy = fmaxf(__fsub_rn(y2, y1), 0.f);
        float inter = __fmul_rn(dx, dy);
        if (inter > 0.f) {   // identical op sequence to main pass
            float uni = __fsub_rn(__fadd_rn(area_p, sgar[j]), inter);
            float iou = __fdiv_rn(inter, fmaxf(uni, EPSF));
            if (iou > bv) { bv = iou; bj = j; }   // strict > == np.argmax first-max
        }
    }

    double c_fl = 0.0, c_gt = 0.0;
    int c_v = 0, c_p = 0;
    if (lane < NC && !(bv > POS_THR)) {   // main pass counted non-pos: flip to pos
        bool was_neg = bv < NEG_THR;      // == valid0 in main pass
        float f1 = focal_shared(obj, true);
        float f0 = focal_shared(obj, false);
        c_fl = (double)f1 - (was_neg ? (double)f0 : 0.0);
        c_v = was_neg ? 0 : 1;
        c_p = 1;
        c_gt = (double)giou_term(px1, py1, px2, py2, sgx1[bj], sgy1[bj], sgx2[bj], sgy2[bj]);
    }
    // fold in per-slice sums (lane == slice; SLICES == 64)
    {
        float sf = Sfl2[b * SLICES + lane];
        float sg = Sgt2[b * SLICES + lane];
        int   sv = Svp2[b * SLICES + lane];
        c_fl += (double)sf; c_gt += (double)sg;
        c_v += sv & 0xFFFF; c_p += sv >> 16;
    }
    for (int off = 32; off; off >>= 1) {
        c_fl += __shfl_down(c_fl, off);
        c_gt += __shfl_down(c_gt, off);
        c_v  += __shfl_down(c_v, off);
        c_p  += __shfl_down(c_p, off);
    }
    if (lane == 0) {
        cls_b[b] = (c_v > 0) ? (float)(c_fl / (double)(c_v > 1 ? c_v : 1)) : 0.f;
        reg_b[b] = (c_p > 0) ? (float)(c_gt / (double)(c_p > 1 ? c_p : 1)) : 0.f;
        npos_b[b] = c_p;
    }

    // final scalar: last image-finisher wave
    __threadfence();
    unsigned t2 = 0;
    if (lane == 0) t2 = atomicAdd(done_final, 1u);
    t2 = __shfl(t2, 0);
    if (t2 == NB - 1) {
        __threadfence();
        volatile float* vc = cls_b;
        volatile float* vr = reg_b;
        volatile int*   vn = npos_b;
        float cv = (lane < NB) ? vc[lane] : 0.f;
        float rv = (lane < NB) ? vr[lane] : 0.f;
        int   nv = (lane < NB) ? vn[lane] : 0;
        for (int off = 32; off; off >>= 1) {
            cv += __shfl_down(cv, off);
            rv += __shfl_down(rv, off);
            nv += __shfl_down(nv, off);
        }
        if (lane == 0) {
            float num_pos = fmaxf((float)nv, 1.f);
            out[0] = cv / (float)NB + 2.0f * (rv / num_pos * (float)NB);
        }
    }
}

// ---------- launcher ----------

extern "C" void kernel_launch(void* const* d_in, const int* in_sizes, int n_in,
                              void* d_out, int out_size, void* d_ws, size_t ws_size,
                              hipStream_t stream) {
    const float* pred = (const float*)d_in[0];   // (32, 65536, 5) f32
    const float* gt   = (const float*)d_in[1];   // (32, 64, 4) f32
    float* out = (float*)d_out;

    // workspace layout (sizes in BYTES; keys2 = NB*SLICES*NGT*8 = 1,048,576 B)
    char* ws = (char*)d_ws;
    unsigned* done_img   = (unsigned*)(ws + 0);                    // 128 B (32 u32)
    unsigned* done_final = (unsigned*)(ws + 128);                  // 4 B (pad to 256)
    unsigned long long* keys2 = (unsigned long long*)(ws + 256);   // 1,048,576 B
    float* Sfl2  = (float*)(ws + 256 + 1048576);                   // 8192 B
    float* Sgt2  = (float*)(ws + 256 + 1048576 + 8192);            // 8192 B
    int*   Svp2  = (int*)(ws + 256 + 1048576 + 16384);             // 8192 B
    float* cls_b = (float*)(ws + 256 + 1048576 + 24576);           // 128 B
    float* reg_b = (float*)(ws + 256 + 1048576 + 24704);           // 128 B
    int*  npos_b = (int*)(ws + 256 + 1048576 + 24832);             // 128 B

    // only the counters need zero-init; everything else is plain-stored each launch
    hipMemsetAsync(d_ws, 0, 256, stream);

    dim3 grid(SLICES, NB);
    fused<<<grid, BLK, 0, stream>>>(pred, gt, keys2, Sfl2, Sgt2, Svp2,
                                    cls_b, reg_b, npos_b, done_img, done_final, out);
}

// Round 9
// 122.990 us; speedup vs baseline: 1.9498x; 1.9498x over previous
//
#include <hip/hip_runtime.h>

#define NB 32
#define NPRED 65536
#define NGT 64
#define BLK 256
#define SLICES 64
#define PPT 4                  // preds per thread; block covers 1024 preds
#define NCB 128                // cumulative bins of 5px
#define CBIN_SCALE 0.2f        // 1/5

#define POS_THR 0.5f
#define NEG_THR 0.4f
#define SCAT_THR 0.1f
#define EPSF 1e-6f

// ---------- exact-op helpers ----------
// Comparison-feeding arithmetic (iou) must be bit-exact vs NumPy fp32 (no FMA
// contraction, IEEE div). Sum-only terms (focal/giou weights) tolerate ulp drift.

__device__ __forceinline__ int cbin(float x) {
    int bi = (int)(x * CBIN_SCALE);         // trunc; monotone non-decreasing
    return max(0, min(NCB - 1, bi));        // clamp keeps monotone -> superset safe
}

__device__ __forceinline__ float focal_shared(float l, bool pos) {
    float e  = expf(-fabsf(l));
    float lg = log1pf(e);
    float rp = 1.f / (1.f + e);              // sigmoid(|l|)
    float p  = (l >= 0.f) ? rp : (1.f - rp); // sigmoid(l); sum-only term
    if (pos) { float q = 1.f - p; return 0.25f * q * q * ((fmaxf(l, 0.f) - l) + lg); }
    return 0.75f * p * p * (fmaxf(l, 0.f) + lg);
}

__device__ __forceinline__ float giou_term(float px1, float py1, float px2, float py2,
                                           float gx1, float gy1, float gx2, float gy2) {
    float x1 = fmaxf(px1, gx1), y1 = fmaxf(py1, gy1);
    float x2 = fminf(px2, gx2), y2 = fminf(py2, gy2);
    float dx = fmaxf(__fsub_rn(x2, x1), 0.f);
    float dy = fmaxf(__fsub_rn(y2, y1), 0.f);
    float inter = __fmul_rn(dx, dy);
    float ap = __fmul_rn(__fsub_rn(px2, px1), __fsub_rn(py2, py1));
    float ag = __fmul_rn(__fsub_rn(gx2, gx1), __fsub_rn(gy2, gy1));
    float uni = __fsub_rn(__fadd_rn(ap, ag), inter);
    float iou = __fdiv_rn(inter, fmaxf(uni, EPSF));
    float ex1 = fminf(px1, gx1), ey1 = fminf(py1, gy1);
    float ex2 = fmaxf(px2, gx2), ey2 = fmaxf(py2, gy2);
    float enc = __fmul_rn(__fsub_rn(ex2, ex1), __fsub_rn(ey2, ey1));
    float giou = __fsub_rn(iou, __fdiv_rn(__fsub_rn(enc, uni), fmaxf(enc, EPSF)));
    return __fsub_rn(1.f, giou);
}

// ---------- Pass A ----------

__global__ __launch_bounds__(BLK) void passA(
    const float* __restrict__ pred, const float* __restrict__ gt,
    unsigned long long* __restrict__ keys,
    double* __restrict__ S_fl, double* __restrict__ S_gt,
    int* __restrict__ vcnt, int* __restrict__ pcnt)
{
    const int b = blockIdx.y;
    const int slice = blockIdx.x;
    const int tid = threadIdx.x;
    const int lane = tid & 63;
    const int wv = tid >> 6;

    // SoA gt (65th entry = zero dummy for branchless inline slots)
    __shared__ float sgx1[NGT + 1], sgy1[NGT + 1], sgx2[NGT + 1], sgy2[NGT + 1], sgar[NGT + 1];
    __shared__ unsigned long long skey[NGT];       // 512 B
    // cumulative candidate masks: [0]=le_x1 (prefix), [1]=ge_x2 (suffix),
    //                             [2]=le_y1 (prefix), [3]=ge_y2 (suffix)
    __shared__ unsigned long long cums[4][NCB];    // 4 KiB
    __shared__ float rfl[BLK / 64], rgt[BLK / 64];
    __shared__ int rvp[BLK / 64];

    // ---- pred loads first: 5 aligned float4 per thread, in flight during setup ----
    const unsigned base_n = (unsigned)(slice * (BLK * PPT));
    const float4* src4 = (const float4*)(pred + (size_t)b * NPRED * 5 + (size_t)base_n * 5)
                         + (size_t)tid * 5;
    float4 q0 = src4[0], q1 = src4[1], q2 = src4[2], q3 = src4[3], q4 = src4[4];

    // ---- gt setup ----
    const float4* gtb = (const float4*)(gt + (size_t)b * NGT * 4);
    float4 gmine;
    if (tid < NGT) gmine = gtb[tid];
    // zero the 4 point arrays (512 ullong, 2 per thread)
    ((unsigned long long*)cums)[tid] = 0ULL;
    ((unsigned long long*)cums)[tid + BLK] = 0ULL;
    if (tid < NGT) {
        sgx1[tid] = gmine.x; sgy1[tid] = gmine.y;
        sgx2[tid] = gmine.z; sgy2[tid] = gmine.w;
        sgar[tid] = __fmul_rn(__fsub_rn(gmine.z, gmine.x), __fsub_rn(gmine.w, gmine.y));
        skey[tid] = 0ULL;
    } else if (tid == NGT) {
        sgx1[NGT] = 0.f; sgy1[NGT] = 0.f; sgx2[NGT] = 0.f; sgy2[NGT] = 0.f; sgar[NGT] = 0.f;
    }
    __syncthreads();

    // point inserts (wave 0 only)
    if (tid < NGT) {
        unsigned long long bit = 1ULL << tid;
        atomicOr(&cums[0][cbin(gmine.x)], bit);   // gx1 -> prefix array
        atomicOr(&cums[1][cbin(gmine.z)], bit);   // gx2 -> suffix array
        atomicOr(&cums[2][cbin(gmine.y)], bit);   // gy1 -> prefix array
        atomicOr(&cums[3][cbin(gmine.w)], bit);   // gy2 -> suffix array
    }
    __syncthreads();

    // wave-parallel cumulative OR: wave wv scans array wv (128 bins, 2/lane).
    {
        unsigned long long v0 = cums[wv][2 * lane];
        unsigned long long v1 = cums[wv][2 * lane + 1];
        unsigned long long v = v0 | v1;
        if ((wv & 1) == 0) {
            // prefix (le): inclusive scan low->high
            #pragma unroll
            for (int off = 1; off < 64; off <<= 1) {
                unsigned long long t = __shfl_up(v, off);
                if (lane >= off) v |= t;
            }
            unsigned long long prev = __shfl_up(v, 1);
            if (lane == 0) prev = 0ULL;
            cums[wv][2 * lane]     = prev | v0;
            cums[wv][2 * lane + 1] = v;
        } else {
            // suffix (ge): inclusive scan high->low
            #pragma unroll
            for (int off = 1; off < 64; off <<= 1) {
                unsigned long long t = __shfl_down(v, off);
                if (lane + off < 64) v |= t;
            }
            unsigned long long nxt = __shfl_down(v, 1);
            if (lane == 63) nxt = 0ULL;
            cums[wv][2 * lane]     = v;
            cums[wv][2 * lane + 1] = v1 | nxt;
        }
    }
    __syncthreads();

    // ---- unpack rows: thread t owns preds 4t..4t+3 (stride-5 in the 20 floats) ----
    const float cxa[PPT] = {q0.x, q1.y, q2.z, q3.w};
    const float cya[PPT] = {q0.y, q1.z, q2.w, q4.x};
    const float wa [PPT] = {q0.z, q1.w, q3.x, q4.y};
    const float ha [PPT] = {q0.w, q2.x, q3.y, q4.z};
    const float oba[PPT] = {q1.x, q2.y, q3.z, q4.w};

    float acc_fl = 0.f, acc_gt = 0.f;
    int acc_vp = 0;   // valid count | pos count<<16

    #pragma unroll
    for (int i = 0; i < PPT; ++i) {
        const float px1 = __fsub_rn(cxa[i], __fmul_rn(wa[i], 0.5f));
        const float py1 = __fsub_rn(cya[i], __fmul_rn(ha[i], 0.5f));
        const float px2 = __fadd_rn(cxa[i], __fmul_rn(wa[i], 0.5f));
        const float py2 = __fadd_rn(cya[i], __fmul_rn(ha[i], 0.5f));
        const float area_p = __fmul_rn(__fsub_rn(px2, px1), __fsub_rn(py2, py1));

        // 4-probe candidate mask (superset of true overlaps; exact gate below)
        unsigned long long m = (cums[1][cbin(px1)] & cums[0][cbin(px2)])
                             & (cums[3][cbin(py1)] & cums[2][cbin(py2)]);

        const unsigned n = base_n + (unsigned)(PPT * tid + i);
        const unsigned long long nkey = (unsigned long long)(~n);

        float best_iou = 0.f;   // zero row -> argmax 0, matches np.argmax
        int best_j = 0;

        // branchless inline-2: dummy index 64 (zero box) -> inter=0 -> no-op
        int j0 = NGT, j1 = NGT;
        if (m) { j0 = __ffsll(m) - 1; m &= m - 1; }
        if (m) { j1 = __ffsll(m) - 1; m &= m - 1; }
        {
            float ax1 = sgx1[j0], ay1 = sgy1[j0], ax2 = sgx2[j0], ay2 = sgy2[j0], aga = sgar[j0];
            float bx1 = sgx1[j1], by1 = sgy1[j1], bx2 = sgx2[j1], by2 = sgy2[j1], agb = sgar[j1];
            float x1 = fmaxf(px1, ax1), y1 = fmaxf(py1, ay1);
            float x2 = fminf(px2, ax2), y2 = fminf(py2, ay2);
            float dx = fmaxf(__fsub_rn(x2, x1), 0.f);
            float dy = fmaxf(__fsub_rn(y2, y1), 0.f);
            float inter = __fmul_rn(dx, dy);
            float uni = __fsub_rn(__fadd_rn(area_p, aga), inter);
            float iou = __fdiv_rn(inter, fmaxf(uni, EPSF));
            iou = (inter > 0.f) ? iou : 0.f;
            if (iou > best_iou) { best_iou = iou; best_j = j0; }
            if (iou > SCAT_THR)
                atomicMax(&skey[j0], (((unsigned long long)__float_as_uint(iou)) << 32) | nkey);

            float X1 = fmaxf(px1, bx1), Y1 = fmaxf(py1, by1);
            float X2 = fminf(px2, bx2), Y2 = fminf(py2, by2);
            float dX = fmaxf(__fsub_rn(X2, X1), 0.f);
            float dY = fmaxf(__fsub_rn(Y2, Y1), 0.f);
            float interB = __fmul_rn(dX, dY);
            float uniB = __fsub_rn(__fadd_rn(area_p, agb), interB);
            float iouB = __fdiv_rn(interB, fmaxf(uniB, EPSF));
            iouB = (interB > 0.f) ? iouB : 0.f;
            if (iouB > best_iou) { best_iou = iouB; best_j = j1; }
            if (iouB > SCAT_THR)
                atomicMax(&skey[j1], (((unsigned long long)__float_as_uint(iouB)) << 32) | nkey);
        }

        // rare remainder (2-way unrolled)
        while (m) {
            int ja = __ffsll(m) - 1; m &= m - 1;
            int jb = -1;
            if (m) { jb = __ffsll(m) - 1; m &= m - 1; }
            int jbc = (jb >= 0) ? jb : NGT;
            float ax1 = sgx1[ja], ay1 = sgy1[ja], ax2 = sgx2[ja], ay2 = sgy2[ja], aga = sgar[ja];
            float bx1 = sgx1[jbc], by1 = sgy1[jbc], bx2 = sgx2[jbc], by2 = sgy2[jbc], agb = sgar[jbc];
            {
                float x1 = fmaxf(px1, ax1), y1 = fmaxf(py1, ay1);
                float x2 = fminf(px2, ax2), y2 = fminf(py2, ay2);
                float dx = fmaxf(__fsub_rn(x2, x1), 0.f);
                float dy = fmaxf(__fsub_rn(y2, y1), 0.f);
                float inter = __fmul_rn(dx, dy);
                if (inter > 0.f) {
                    float uni = __fsub_rn(__fadd_rn(area_p, aga), inter);
                    float iou = __fdiv_rn(inter, fmaxf(uni, EPSF));
                    if (iou > best_iou) { best_iou = iou; best_j = ja; }
                    if (iou > SCAT_THR)
                        atomicMax(&skey[ja], (((unsigned long long)__float_as_uint(iou)) << 32) | nkey);
                }
            }
            if (jb >= 0) {
                float x1 = fmaxf(px1, bx1), y1 = fmaxf(py1, by1);
                float x2 = fminf(px2, bx2), y2 = fminf(py2, by2);
                float dx = fmaxf(__fsub_rn(x2, x1), 0.f);
                float dy = fmaxf(__fsub_rn(y2, y1), 0.f);
                float inter = __fmul_rn(dx, dy);
                if (inter > 0.f) {
                    float uni = __fsub_rn(__fadd_rn(area_p, agb), inter);
                    float iou = __fdiv_rn(inter, fmaxf(uni, EPSF));
                    if (iou > best_iou) { best_iou = iou; best_j = jb; }
                    if (iou > SCAT_THR)
                        atomicMax(&skey[jb], (((unsigned long long)__float_as_uint(iou)) << 32) | nkey);
                }
            }
        }

        const bool pos0   = best_iou > POS_THR;
        const bool negf   = best_iou < NEG_THR;
        const bool valid0 = pos0 || negf;
        if (valid0) acc_fl += focal_shared(oba[i], pos0);
        if (pos0) {
            acc_gt += giou_term(px1, py1, px2, py2,
                                sgx1[best_j], sgy1[best_j], sgx2[best_j], sgy2[best_j]);
        }
        acc_vp += (valid0 ? 1 : 0) | (pos0 ? 0x10000 : 0);
    }

    // one reduction + one global-atomic set per block
    for (int off = 32; off; off >>= 1) {
        acc_fl += __shfl_down(acc_fl, off);
        acc_gt += __shfl_down(acc_gt, off);
        acc_vp += __shfl_down(acc_vp, off);
    }
    if (lane == 0) { rfl[wv] = acc_fl; rgt[wv] = acc_gt; rvp[wv] = acc_vp; }
    __syncthreads();   // also orders all skey LDS atomics before the drain
    if (tid == 0) {
        float sfl = 0.f, sgt2 = 0.f; int svp = 0;
        #pragma unroll
        for (int i = 0; i < BLK / 64; ++i) { sfl += rfl[i]; sgt2 += rgt[i]; svp += rvp[i]; }
        atomicAdd(&S_fl[b], (double)sfl);
        atomicAdd(&S_gt[b], (double)sgt2);
        atomicAdd(&vcnt[b], svp & 0xFFFF);
        atomicAdd(&pcnt[b], svp >> 16);
    }
    if (tid < NGT) {
        unsigned long long k = skey[tid];
        if (k) atomicMax(&keys[b * NGT + tid], k);
    }
}

// ---------- Pass B+C fused: scatter corrections + final scalar (last-block) ----------

__global__ __launch_bounds__(64) void passBC(
    const float* __restrict__ pred, const float* __restrict__ gt,
    const unsigned long long* __restrict__ keys,
    const double* __restrict__ S_fl, const double* __restrict__ S_gt,
    const int* __restrict__ vcnt, const int* __restrict__ pcnt,
    float* __restrict__ cls_b, float* __restrict__ reg_b, int* __restrict__ npos_b,
    unsigned* __restrict__ done, float* __restrict__ out)
{
    const int b = blockIdx.x;
    const int lane = threadIdx.x;   // one wave; lane == gt index initially

    __shared__ float4 sgt[NGT];
    __shared__ unsigned cn_list[NGT];

    const float4* gtb = (const float4*)(gt + (size_t)b * NGT * 4);
    float4 gj = gtb[lane];
    sgt[lane] = gj;

    unsigned long long key = keys[b * NGT + lane];
    float miou = __uint_as_float((unsigned)(key >> 32));
    unsigned n = ~((unsigned)(key & 0xFFFFFFFFULL));
    bool qual = miou > SCAT_THR;   // key==0 -> miou=0 -> false

    // dedupe: keep first qualifying lane per pred index (ref .at[].max semantics)
    bool unique = qual;
    for (int j2 = 0; j2 < NGT; ++j2) {
        unsigned bn = __shfl(n, j2);
        int bq = __shfl((int)qual, j2);
        if (bq && j2 < lane && bn == n) unique = false;
    }
    unsigned long long mask = __ballot(unique ? 1 : 0);
    int NC = __popcll(mask);
    int slot = __popcll(mask & ((1ULL << lane) - 1ULL));
    if (unique) cn_list[slot] = n;
    __syncthreads();

    // candidate-parallel: lane l recomputes candidate l's full best_gt argmax
    float cx = 0.f, cy = 0.f, w = 0.f, h = 0.f, obj = 0.f;
    if (lane < NC) {
        const float* p = pred + (size_t)b * NPRED * 5 + (size_t)cn_list[lane] * 5;
        cx = p[0]; cy = p[1]; w = p[2]; h = p[3]; obj = p[4];
    }
    float px1 = __fsub_rn(cx, __fmul_rn(w, 0.5f));
    float py1 = __fsub_rn(cy, __fmul_rn(h, 0.5f));
    float px2 = __fadd_rn(cx, __fmul_rn(w, 0.5f));
    float py2 = __fadd_rn(cy, __fmul_rn(h, 0.5f));
    float area_p = __fmul_rn(__fsub_rn(px2, px1), __fsub_rn(py2, py1));

    float bv = 0.f; int bj = 0;
    #pragma unroll 4
    for (int j = 0; j < NGT; ++j) {
        float4 g = sgt[j];   // uniform -> broadcast
        float x1 = fmaxf(px1, g.x), y1 = fmaxf(py1, g.y);
        float x2 = fminf(px2, g.z), y2 = fminf(py2, g.w);
        float dx = fmaxf(__fsub_rn(x2, x1), 0.f);
        float dy = fmaxf(__fsub_rn(y2, y1), 0.f);
        float inter = __fmul_rn(dx, dy);
        if (inter > 0.f) {   // identical op sequence to passA
            float ag = __fmul_rn(__fsub_rn(g.z, g.x), __fsub_rn(g.w, g.y));
            float uni = __fsub_rn(__fadd_rn(area_p, ag), inter);
            float iou = __fdiv_rn(inter, fmaxf(uni, EPSF));
            if (iou > bv) { bv = iou; bj = j; }   // strict > == np.argmax first-max
        }
    }

    double add_fl = 0.0, add_gt = 0.0;
    int add_v = 0, add_p = 0;
    if (lane < NC && !(bv > POS_THR)) {   // passA counted non-pos: flip to pos
        bool was_neg = bv < NEG_THR;      // == valid0 in passA
        float f1 = focal_shared(obj, true);
        float f0 = focal_shared(obj, false);
        add_fl = (double)f1 - (was_neg ? (double)f0 : 0.0);
        add_v = was_neg ? 0 : 1;
        add_p = 1;
        float4 gb = sgt[bj];
        add_gt = (double)giou_term(px1, py1, px2, py2, gb.x, gb.y, gb.z, gb.w);
    }

    for (int off = 32; off; off >>= 1) {
        add_fl += __shfl_down(add_fl, off);
        add_gt += __shfl_down(add_gt, off);
        add_v  += __shfl_down(add_v, off);
        add_p  += __shfl_down(add_p, off);
    }

    if (lane == 0) {
        double sfl = S_fl[b] + add_fl;
        double sgt2 = S_gt[b] + add_gt;
        int v = vcnt[b] + add_v;
        int pc = pcnt[b] + add_p;
        cls_b[b] = (v > 0) ? (float)(sfl / (double)(v > 1 ? v : 1)) : 0.f;
        reg_b[b] = (pc > 0) ? (float)(sgt2 / (double)(pc > 1 ? pc : 1)) : 0.f;
        npos_b[b] = pc;
    }

    // last-block final reduction (device-scope atomics + fences per G16;
    // only 32 blocks here, fence cost negligible — unlike the R8 fusion)
    __threadfence();
    unsigned t = 0;
    if (lane == 0) t = atomicAdd(done, 1u);
    t = __shfl(t, 0);
    if (t == NB - 1) {
        __threadfence();
        volatile float* vc = cls_b;
        volatile float* vr = reg_b;
        volatile int*   vn = npos_b;
        float cv = (lane < NB) ? vc[lane] : 0.f;
        float rv = (lane < NB) ? vr[lane] : 0.f;
        int   nv = (lane < NB) ? vn[lane] : 0;
        for (int off = 32; off; off >>= 1) {
            cv += __shfl_down(cv, off);
            rv += __shfl_down(rv, off);
            nv += __shfl_down(nv, off);
        }
        if (lane == 0) {
            float num_pos = fmaxf((float)nv, 1.f);
            out[0] = cv / (float)NB + 2.0f * (rv / num_pos * (float)NB);
        }
    }
}

// ---------- launcher ----------

extern "C" void kernel_launch(void* const* d_in, const int* in_sizes, int n_in,
                              void* d_out, int out_size, void* d_ws, size_t ws_size,
                              hipStream_t stream) {
    const float* pred = (const float*)d_in[0];   // (32, 65536, 5) f32
    const float* gt   = (const float*)d_in[1];   // (32, 64, 4) f32
    float* out = (float*)d_out;

    char* ws = (char*)d_ws;
    unsigned long long* keys = (unsigned long long*)(ws + 0);       // 16384 B
    double* S_fl   = (double*)(ws + 16384);                         // 256 B
    double* S_gt   = (double*)(ws + 16640);                         // 256 B
    int* vcnt      = (int*)(ws + 16896);                            // 128 B
    int* pcnt      = (int*)(ws + 17024);                            // 128 B
    float* cls_b   = (float*)(ws + 17152);                          // 128 B
    float* reg_b   = (float*)(ws + 17280);                          // 128 B
    int* npos_b    = (int*)(ws + 17408);                            // 128 B
    unsigned* done = (unsigned*)(ws + 17536);                       // 4 B

    hipMemsetAsync(d_ws, 0, 17664, stream);

    dim3 gridA(SLICES, NB);
    passA<<<gridA, BLK, 0, stream>>>(pred, gt, keys, S_fl, S_gt, vcnt, pcnt);
    passBC<<<NB, 64, 0, stream>>>(pred, gt, keys, S_fl, S_gt, vcnt, pcnt,
                                  cls_b, reg_b, npos_b, done, out);
}